// Round 10
// baseline (949.223 us; speedup 1.0000x reference)
//
#include <hip/hip_runtime.h>
#include <stdint.h>

typedef unsigned short u16;
typedef unsigned int   u32;

#define NNODES 10000
#define NEDGES 20000
#define ETOT   30000
#define NHEADS 12
#define CDIM   768
#define FDIM   768
#define KDIM   9216
#define NGRAPH 64
#define MPAD   10240   // 80*128
#define SPLITS 4
#define KCH    (KDIM / SPLITS)   // 2304
#define NEG_SLOPE 0.2f
#define DMAX   32      // max in-degree incl. self-loop; max of 10000 Poisson(2) ~ 14

typedef __attribute__((ext_vector_type(8))) short short8;
typedef __attribute__((ext_vector_type(4))) float f32x4;

__device__ __forceinline__ u16 f32_bf16(float f) {
  u32 u = __float_as_uint(f);
  u = (u + 0x7FFFu + ((u >> 16) & 1u)) >> 16;
  return (u16)u;
}

// ---------------- CSR build ----------------
__global__ void k_count(const int* __restrict__ dste, int* __restrict__ counts) {
  int e = blockIdx.x * blockDim.x + threadIdx.x;
  if (e >= ETOT) return;
  int dst;
  if (e < NEDGES) dst = dste[e]; else dst = e - NEDGES;
  atomicAdd(&counts[dst], 1);
}

__global__ void k_scan(const int* __restrict__ counts, int* __restrict__ offs) {
  __shared__ int part[256];
  int t = threadIdx.x;
  const int chunk = 40;
  int beg = t * chunk;
  int end = beg + chunk; if (end > NNODES) end = NNODES;
  int s = 0;
  for (int i = beg; i < end && i < NNODES; i++) s += counts[i];
  part[t] = s;
  __syncthreads();
  for (int d = 1; d < 256; d <<= 1) {
    int v = (t >= d) ? part[t - d] : 0;
    __syncthreads();
    part[t] += v;
    __syncthreads();
  }
  int base = (t == 0) ? 0 : part[t - 1];
  for (int i = beg; i < end && i < NNODES; i++) { offs[i] = base; base += counts[i]; }
  if (t == 255) offs[NNODES] = base;
}

__global__ void k_seed(const int* __restrict__ offs, int* __restrict__ cursor) {
  int n = blockIdx.x * blockDim.x + threadIdx.x;
  if (n < NNODES) cursor[n] = offs[n];
}

__global__ void k_scatter(const int* __restrict__ dste, int* __restrict__ cursor,
                          int* __restrict__ elist) {
  int e = blockIdx.x * blockDim.x + threadIdx.x;
  if (e >= ETOT) return;
  int dst;
  if (e < NEDGES) dst = dste[e]; else dst = e - NEDGES;
  int pos = atomicAdd(&cursor[dst], 1);
  elist[pos] = e;
}

// ------- Ut[o*768+k] = sum_c W[k, h*768+c] * a[h, c] ; 4 waves x 6 o's per block -------
__global__ void k_U(const float* __restrict__ W, const float* __restrict__ a_src,
                    const float* __restrict__ a_dst, float* __restrict__ Ut) {
  int k = blockIdx.x;
  int t = threadIdx.x, w = t >> 6, l = t & 63;
  const float* Wrow = W + (size_t)k * KDIM;
#pragma unroll
  for (int q = 0; q < 6; q++) {
    int o = w * 6 + q;
    int h = (o < 12) ? o : o - 12;
    const float* av = (o < 12) ? (a_src + h * CDIM) : (a_dst + h * CDIM);
    const float* wr = Wrow + h * CDIM;
    float p = 0.f;
    for (int c = l; c < CDIM; c += 64) p += wr[c] * av[c];
#pragma unroll
    for (int d = 32; d > 0; d >>= 1) p += __shfl_down(p, d, 64);
    if (l == 0) Ut[o * FDIM + k] = p;
  }
}

// ---- sd: Ut staged in LDS once per block; 20 nodes/block (5 per wave) ----
__global__ void k_sd(const float* __restrict__ xin, const float* __restrict__ Ut,
                     float* __restrict__ sd) {
  __shared__ float UtS[24 * FDIM];   // 73728 B
  int t = threadIdx.x, w = t >> 6, l = t & 63;
  const float4* U4 = (const float4*)Ut;
  float4* S4 = (float4*)UtS;
  for (int i = t; i < 24 * FDIM / 4; i += 256) S4[i] = U4[i];
  __syncthreads();
#pragma unroll
  for (int rep = 0; rep < 5; rep++) {
    int n = blockIdx.x * 20 + w * 5 + rep;
    if (n >= NNODES) continue;
    const float* xr = xin + (size_t)n * FDIM;
    float4 x0 = *(const float4*)(xr + 4 * l);
    float4 x1 = *(const float4*)(xr + 4 * l + 256);
    float4 x2 = *(const float4*)(xr + 4 * l + 512);
#pragma unroll
    for (int o = 0; o < 24; o++) {
      const float4* up = (const float4*)(UtS + o * FDIM + 4 * l);
      float4 u0 = up[0];
      float4 u1 = up[64];
      float4 u2 = up[128];
      float a = x0.x * u0.x + x0.y * u0.y + x0.z * u0.z + x0.w * u0.w
              + x1.x * u1.x + x1.y * u1.y + x1.z * u1.z + x1.w * u1.w
              + x2.x * u2.x + x2.y * u2.y + x2.z * u2.z + x2.w * u2.w;
#pragma unroll
      for (int d = 32; d > 0; d >>= 1) a += __shfl_xor(a, d, 64);
      if (l == 0) sd[n * 24 + o] = a;
    }
  }
}

// -------- Bt[c, h*768+k] = W[k, h*768+c], bf16 (B^T row-major for the GEMM) --------
__global__ void k_trans(const float* __restrict__ W, u16* __restrict__ Bt) {
  int h = blockIdx.z;
  int kt = blockIdx.x * 32, ct = blockIdx.y * 32;
  int tx = threadIdx.x, ty = threadIdx.y;
  __shared__ float tile[32][33];
#pragma unroll
  for (int r = 0; r < 4; r++)
    tile[ty + 8 * r][tx] = W[(size_t)(kt + ty + 8 * r) * KDIM + h * CDIM + ct + tx];
  __syncthreads();
#pragma unroll
  for (int r = 0; r < 4; r++)
    Bt[(size_t)(ct + ty + 8 * r) * KDIM + h * CDIM + kt + tx] = f32_bf16(tile[tx][ty + 8 * r]);
}

// ---- fused attention softmax + aggregation, ONE WAVE PER NODE ----
// Wave-private LDS (no __syncthreads): LDS ops are in-order within a wave's
// instruction stream; wave_barrier() pins scheduling across phases.
__global__ void k_att(const float* __restrict__ xin, const int* __restrict__ ei,
                      const int* __restrict__ offs, const int* __restrict__ elist,
                      const float* __restrict__ sd, u16* __restrict__ agg) {
  int t = threadIdx.x, w = t >> 6, l = t & 63;
  int n = blockIdx.x * 4 + w;
  __shared__ int   srcsS[4][DMAX];
  __shared__ float alphS[4][NHEADS * DMAX];
  if (n >= NNODES) return;          // no block barriers below -> divergent exit safe
  int* srcs = srcsS[w];
  float* alph = alphS[w];
  int beg = offs[n];
  int deg = offs[n + 1] - beg;
  if (deg > DMAX) deg = DMAX;
  if (l < deg) {
    int e = elist[beg + l];
    srcs[l] = (e < NEDGES) ? ei[e] : e - NEDGES;
  }
  __builtin_amdgcn_wave_barrier();
  // logits + leaky-relu, pairs (i,h) strided across lanes
  for (int p = l; p < deg * NHEADS; p += 64) {
    int i = p / NHEADS, h = p - i * NHEADS;
    float v = sd[srcs[i] * 24 + h] + sd[n * 24 + 12 + h];
    v = (v > 0.f) ? v : NEG_SLOPE * v;
    alph[h * DMAX + i] = v;
  }
  __builtin_amdgcn_wave_barrier();
  // per-head softmax: lane h owns head h
  if (l < NHEADS) {
    float m = -1e30f;
    for (int i = 0; i < deg; i++) m = fmaxf(m, alph[l * DMAX + i]);
    float s = 0.f;
    for (int i = 0; i < deg; i++) {
      float ex = expf(alph[l * DMAX + i] - m);
      alph[l * DMAX + i] = ex;
      s += ex;
    }
    float inv = 1.f / (s + 1e-16f);
    for (int i = 0; i < deg; i++) alph[l * DMAX + i] *= inv;
  }
  __builtin_amdgcn_wave_barrier();
  // aggregation: 3 passes of 256 floats; lane l covers floats [4l, 4l+4)
  u16* outr = agg + (size_t)n * KDIM + 4 * l;
#pragma unroll
  for (int pass = 0; pass < 3; pass++) {
    float4 acc[NHEADS];
#pragma unroll
    for (int h = 0; h < NHEADS; h++) acc[h] = make_float4(0.f, 0.f, 0.f, 0.f);
    for (int i = 0; i < deg; i++) {
      float4 xv = *(const float4*)(xin + (size_t)srcs[i] * FDIM + pass * 256 + 4 * l);
#pragma unroll
      for (int h = 0; h < NHEADS; h++) {
        float a = alph[h * DMAX + i];
        acc[h].x += a * xv.x; acc[h].y += a * xv.y;
        acc[h].z += a * xv.z; acc[h].w += a * xv.w;
      }
    }
#pragma unroll
    for (int h = 0; h < NHEADS; h++) {
      ushort4 pk;
      pk.x = f32_bf16(acc[h].x); pk.y = f32_bf16(acc[h].y);
      pk.z = f32_bf16(acc[h].z); pk.w = f32_bf16(acc[h].w);
      *(ushort4*)(outr + h * CDIM + pass * 256) = pk;
    }
  }
}

// ---- GEMM (r7 best-measured): register staging buffer_load->VGPR->ds_write,
//      2 staging sets (1 tile ahead). 128x128 block, 64x64 wave, split-K=4,
//      XCD swizzle. 248-251 us measured; 3-set variant spills (r8) — do not deepen. ----
__global__ __launch_bounds__(256, 3) void k_gemm(const u16* __restrict__ A,
    const u16* __restrict__ B, float* __restrict__ C,
    const float* __restrict__ bias, float scale) {
  __shared__ __align__(16) u16 As[2][128 * 32];
  __shared__ __align__(16) u16 Bs[2][128 * 32];
  int t = threadIdx.x;
  int w = t >> 6, l = t & 63;
  int lin = blockIdx.x;
  int xcd = lin & 7;
  int s = lin >> 3;                    // 0..239
  int kz = xcd >> 1;                   // K split 0..3, pinned to XCD pair
  int colt = (xcd & 1) * 3 + (s % 3);  // 0..5 (128-col tiles)
  int y = s / 3;                       // 0..79 (128-row tiles)
  int col0 = colt * 128;
  int row0 = y * 128;
  int kbeg = kz * KCH;
  int wm = (w >> 1) * 64, wn = (w & 1) * 64;
  f32x4 acc[4][4] = {};
  int idx0 = t * 8;                    // elem index in 128x32 tile, chunk 0 (rows 0-63)
  int idx1 = idx0 + 2048;              // chunk 1 (rows 64-127)
  const u16* Ag0 = A + (size_t)(row0 + (idx0 >> 5)) * KDIM + (idx0 & 31) + kbeg;
  const u16* Ag1 = A + (size_t)(row0 + (idx1 >> 5)) * KDIM + (idx1 & 31) + kbeg;
  const u16* Bg0 = B + (size_t)(col0 + (idx0 >> 5)) * KDIM + (idx0 & 31) + kbeg;
  const u16* Bg1 = B + (size_t)(col0 + (idx1 >> 5)) * KDIM + (idx1 & 31) + kbeg;
  int lr = l & 15, lk = (l >> 4) * 8;

  short8 ra0, ra1, rb0, rb1;           // staging registers (tile in flight)
  auto gload = [&](int k0) {
    ra0 = *(const short8*)(Ag0 + k0);
    ra1 = *(const short8*)(Ag1 + k0);
    rb0 = *(const short8*)(Bg0 + k0);
    rb1 = *(const short8*)(Bg1 + k0);
  };
  auto swrite = [&](int buf) {
    *(short8*)(&As[buf][idx0]) = ra0;
    *(short8*)(&As[buf][idx1]) = ra1;
    *(short8*)(&Bs[buf][idx0]) = rb0;
    *(short8*)(&Bs[buf][idx1]) = rb1;
  };

  gload(0);
  swrite(0);                 // waits vmcnt for tile-0 loads only
  gload(32);                 // tile-1 loads go in flight, cross the barrier
  __syncthreads();           // lgkmcnt for ds_writes
  const int NIT = KCH / 32;  // 72
  int cur = 0;
  for (int it = 0; it < NIT; it++) {
    short8 af[4], bf[4];
#pragma unroll
    for (int i = 0; i < 4; i++) af[i] = *(const short8*)(&As[cur][(wm + i * 16 + lr) * 32 + lk]);
#pragma unroll
    for (int j = 0; j < 4; j++) bf[j] = *(const short8*)(&Bs[cur][(wn + j * 16 + lr) * 32 + lk]);
#pragma unroll
    for (int i = 0; i < 4; i++)
#pragma unroll
      for (int j = 0; j < 4; j++)
        acc[i][j] = __builtin_amdgcn_mfma_f32_16x16x32_bf16(af[i], bf[j], acc[i][j], 0, 0, 0);
    if (it + 1 < NIT) {
      swrite(cur ^ 1);                       // consumes loads issued last iter (vmcnt(N>0))
      if (it + 2 < NIT) gload((it + 2) * 32);  // next loads stay in flight across barrier
    }
    __syncthreads();
    cur ^= 1;
  }

  int lg = l >> 4;
#pragma unroll
  for (int i = 0; i < 4; i++)
#pragma unroll
    for (int j = 0; j < 4; j++) {
      int col = col0 + wn + j * 16 + lr;
      float badd = (kz == 0) ? bias[col] : 0.f;
#pragma unroll
      for (int r = 0; r < 4; r++) {
        int row = row0 + wm + i * 16 + lg * 4 + r;
        unsafeAtomicAdd(&C[(size_t)row * FDIM + col], acc[i][j][r] * scale + badd);
      }
    }
}

// ---------------- graph mean pool (batch is sorted) ----------------
__global__ void k_pool(const float* __restrict__ h2, const int* __restrict__ batch,
                       float* __restrict__ g) {
  int gi = blockIdx.x;
  int c = blockIdx.y * 256 + threadIdx.x;
  int lo = 0, hi = NNODES;
  while (lo < hi) { int mid = (lo + hi) >> 1; if (batch[mid] < gi) lo = mid + 1; else hi = mid; }
  int start = lo;
  lo = start; hi = NNODES;
  while (lo < hi) { int mid = (lo + hi) >> 1; if (batch[mid] < gi + 1) lo = mid + 1; else hi = mid; }
  int end = lo;
  int cnt = end - start; if (cnt < 1) cnt = 1;
  float inv = 1.f / (float)cnt;
  float s = 0.f;
  for (int n = start; n < end; n++) s += h2[(size_t)n * FDIM + c];
  g[gi * FDIM + c] = s * inv;
}

// ---------------- MLP head ----------------
__global__ void k_mlp(const float* __restrict__ g, const float* __restrict__ w1,
                      const float* __restrict__ b1, const float* __restrict__ w2,
                      const float* __restrict__ b2, float* __restrict__ out) {
  int gi = blockIdx.x;
  int t = threadIdx.x;  // 128
  __shared__ float gs[FDIM];
  __shared__ float zs[128];
  for (int i = t; i < FDIM; i += 128) gs[i] = g[gi * FDIM + i];
  __syncthreads();
  float a = b1[t];
  for (int k = 0; k < FDIM; k++) a += gs[k] * w1[k * 128 + t];
  zs[t] = (a > 0.f) ? a : 0.f;
  __syncthreads();
  if (t < 4) {
    float o = b2[t];
    for (int i = 0; i < 128; i++) o += zs[i] * w2[i * 4 + t];
    out[gi * 4 + t] = o;
  }
}

extern "C" void kernel_launch(void* const* d_in, const int* in_sizes, int n_in,
                              void* d_out, int out_size, void* d_ws, size_t ws_size,
                              hipStream_t stream) {
  const float* x    = (const float*)d_in[0];
  const int*   ei   = (const int*)d_in[1];
  const int*   batch= (const int*)d_in[2];
  const float* W1   = (const float*)d_in[3];
  const float* as1  = (const float*)d_in[4];
  const float* ad1  = (const float*)d_in[5];
  const float* b1   = (const float*)d_in[6];
  const float* W2   = (const float*)d_in[7];
  const float* as2  = (const float*)d_in[8];
  const float* ad2  = (const float*)d_in[9];
  const float* b2   = (const float*)d_in[10];
  const float* mw1  = (const float*)d_in[11];
  const float* mb1  = (const float*)d_in[12];
  const float* mw2  = (const float*)d_in[13];
  const float* mb2  = (const float*)d_in[14];
  float* out = (float*)d_out;
  (void)in_sizes; (void)n_in; (void)out_size; (void)ws_size;

  char* wsb = (char*)d_ws;
  size_t off = 0;
  auto alloc = [&](size_t bytes) -> void* {
    void* p = wsb + off;
    off += (bytes + 255) & ~(size_t)255;
    return p;
  };
  u16*  agg    = (u16*)alloc((size_t)MPAD * KDIM * 2);     // 188.7 MB
  u16*  Bt     = (u16*)alloc((size_t)FDIM * KDIM * 2);     // 14.2 MB
  float* h1    = (float*)alloc((size_t)MPAD * FDIM * 4);   // 31.5 MB
  float* h2    = (float*)alloc((size_t)MPAD * FDIM * 4);   // 31.5 MB
  float* sd    = (float*)alloc((size_t)NNODES * 24 * 4);
  float* Ut    = (float*)alloc((size_t)FDIM * 24 * 4);
  int*  counts = (int*)alloc((size_t)NNODES * 4);
  int*  offs   = (int*)alloc((size_t)(NNODES + 1) * 4);
  int*  cursor = (int*)alloc((size_t)NNODES * 4);
  int*  elist  = (int*)alloc((size_t)ETOT * 4);
  float* gbuf  = (float*)alloc((size_t)NGRAPH * FDIM * 4);

  // CSR by dst (edges identical for both layers)
  hipMemsetAsync(counts, 0, NNODES * 4, stream);
  k_count<<<(ETOT + 255) / 256, 256, 0, stream>>>(ei + NEDGES, counts);
  k_scan<<<1, 256, 0, stream>>>(counts, offs);
  k_seed<<<(NNODES + 255) / 256, 256, 0, stream>>>(offs, cursor);
  k_scatter<<<(ETOT + 255) / 256, 256, 0, stream>>>(ei + NEDGES, cursor, elist);

  for (int layer = 0; layer < 2; layer++) {
    const float* xin  = layer ? h1  : x;
    const float* W    = layer ? W2  : W1;
    const float* asrc = layer ? as2 : as1;
    const float* adst = layer ? ad2 : ad1;
    const float* bb   = layer ? b2  : b1;
    float* hout       = layer ? h2  : h1;

    k_U<<<FDIM, 256, 0, stream>>>(W, asrc, adst, Ut);
    k_sd<<<(NNODES + 19) / 20, 256, 0, stream>>>(xin, Ut, sd);
    k_trans<<<dim3(24, 24, 12), dim3(32, 8), 0, stream>>>(W, Bt);
    hipMemsetAsync(hout, 0, (size_t)MPAD * FDIM * 4, stream);
    k_att<<<(NNODES + 3) / 4, 256, 0, stream>>>(xin, ei, offs, elist, sd, agg);
    k_gemm<<<1920, 256, 0, stream>>>(agg, Bt, hout, bb, 1.f / 12.f);
  }

  k_pool<<<dim3(NGRAPH, 3), 256, 0, stream>>>(h2, batch, gbuf);
  k_mlp<<<NGRAPH, 128, 0, stream>>>(gbuf, mw1, mb1, mw2, mb2, out);
}

// Round 12
// 913.682 us; speedup vs baseline: 1.0389x; 1.0389x over previous
//
#include <hip/hip_runtime.h>
#include <stdint.h>

typedef unsigned short u16;
typedef unsigned int   u32;

#define NNODES 10000
#define NEDGES 20000
#define ETOT   30000
#define NHEADS 12
#define CDIM   768
#define FDIM   768
#define KDIM   9216
#define NGRAPH 64
#define MPAD   10112   // 79*128 >= NNODES ; keeps total ws <= 264 MB (256 MiB budget!)
#define NEG_SLOPE 0.2f
#define DMAX   32      // max in-degree incl. self-loop; max of 10000 Poisson(2) ~ 14

typedef __attribute__((ext_vector_type(8))) short short8;
typedef __attribute__((ext_vector_type(4))) float f32x4;

__device__ __forceinline__ u16 f32_bf16(float f) {
  u32 u = __float_as_uint(f);
  u = (u + 0x7FFFu + ((u >> 16) & 1u)) >> 16;
  return (u16)u;
}
__device__ __forceinline__ float bf16_f32(u16 v) {
  return __uint_as_float(((u32)v) << 16);
}

// ---------------- CSR build ----------------
__global__ void k_count(const int* __restrict__ dste, int* __restrict__ counts) {
  int e = blockIdx.x * blockDim.x + threadIdx.x;
  if (e >= ETOT) return;
  int dst;
  if (e < NEDGES) dst = dste[e]; else dst = e - NEDGES;
  atomicAdd(&counts[dst], 1);
}

__global__ void k_scan(const int* __restrict__ counts, int* __restrict__ offs) {
  __shared__ int part[256];
  int t = threadIdx.x;
  const int chunk = 40;
  int beg = t * chunk;
  int end = beg + chunk; if (end > NNODES) end = NNODES;
  int s = 0;
  for (int i = beg; i < end && i < NNODES; i++) s += counts[i];
  part[t] = s;
  __syncthreads();
  for (int d = 1; d < 256; d <<= 1) {
    int v = (t >= d) ? part[t - d] : 0;
    __syncthreads();
    part[t] += v;
    __syncthreads();
  }
  int base = (t == 0) ? 0 : part[t - 1];
  for (int i = beg; i < end && i < NNODES; i++) { offs[i] = base; base += counts[i]; }
  if (t == 255) offs[NNODES] = base;
}

__global__ void k_seed(const int* __restrict__ offs, int* __restrict__ cursor) {
  int n = blockIdx.x * blockDim.x + threadIdx.x;
  if (n < NNODES) cursor[n] = offs[n];
}

__global__ void k_scatter(const int* __restrict__ dste, int* __restrict__ cursor,
                          int* __restrict__ elist) {
  int e = blockIdx.x * blockDim.x + threadIdx.x;
  if (e >= ETOT) return;
  int dst;
  if (e < NEDGES) dst = dste[e]; else dst = e - NEDGES;
  int pos = atomicAdd(&cursor[dst], 1);
  elist[pos] = e;
}

// ------- Ut[o*768+k] = sum_c W[k, h*768+c] * a[h, c] ; 4 waves x 6 o's per block -------
__global__ void k_U(const float* __restrict__ W, const float* __restrict__ a_src,
                    const float* __restrict__ a_dst, float* __restrict__ Ut) {
  int k = blockIdx.x;
  int t = threadIdx.x, w = t >> 6, l = t & 63;
  const float* Wrow = W + (size_t)k * KDIM;
#pragma unroll
  for (int q = 0; q < 6; q++) {
    int o = w * 6 + q;
    int h = (o < 12) ? o : o - 12;
    const float* av = (o < 12) ? (a_src + h * CDIM) : (a_dst + h * CDIM);
    const float* wr = Wrow + h * CDIM;
    float p = 0.f;
    for (int c = l; c < CDIM; c += 64) p += wr[c] * av[c];
#pragma unroll
    for (int d = 32; d > 0; d >>= 1) p += __shfl_down(p, d, 64);
    if (l == 0) Ut[o * FDIM + k] = p;
  }
}

// ---- sd: Ut staged in LDS once per block; 20 nodes/block. Also writes xbf (GEMM A). ----
__global__ void k_sd(const float* __restrict__ xin, const float* __restrict__ Ut,
                     float* __restrict__ sd, u16* __restrict__ xbf) {
  __shared__ float UtS[24 * FDIM];   // 73728 B
  int t = threadIdx.x, w = t >> 6, l = t & 63;
  const float4* U4 = (const float4*)Ut;
  float4* S4 = (float4*)UtS;
  for (int i = t; i < 24 * FDIM / 4; i += 256) S4[i] = U4[i];
  __syncthreads();
#pragma unroll
  for (int rep = 0; rep < 5; rep++) {
    int n = blockIdx.x * 20 + w * 5 + rep;
    if (n >= NNODES) continue;
    const float* xr = xin + (size_t)n * FDIM;
    float4 x0 = *(const float4*)(xr + 4 * l);
    float4 x1 = *(const float4*)(xr + 4 * l + 256);
    float4 x2 = *(const float4*)(xr + 4 * l + 512);
    // bf16 copy for the GEMM A operand
    u16* xb = xbf + (size_t)n * FDIM + 4 * l;
    ushort4 p0, p1, p2;
    p0.x = f32_bf16(x0.x); p0.y = f32_bf16(x0.y); p0.z = f32_bf16(x0.z); p0.w = f32_bf16(x0.w);
    p1.x = f32_bf16(x1.x); p1.y = f32_bf16(x1.y); p1.z = f32_bf16(x1.z); p1.w = f32_bf16(x1.w);
    p2.x = f32_bf16(x2.x); p2.y = f32_bf16(x2.y); p2.z = f32_bf16(x2.z); p2.w = f32_bf16(x2.w);
    *(ushort4*)xb = p0;
    *(ushort4*)(xb + 256) = p1;
    *(ushort4*)(xb + 512) = p2;
#pragma unroll
    for (int o = 0; o < 24; o++) {
      const float4* up = (const float4*)(UtS + o * FDIM + 4 * l);
      float4 u0 = up[0];
      float4 u1 = up[64];
      float4 u2 = up[128];
      float a = x0.x * u0.x + x0.y * u0.y + x0.z * u0.z + x0.w * u0.w
              + x1.x * u1.x + x1.y * u1.y + x1.z * u1.z + x1.w * u1.w
              + x2.x * u2.x + x2.y * u2.y + x2.z * u2.z + x2.w * u2.w;
#pragma unroll
      for (int d = 32; d > 0; d >>= 1) a += __shfl_xor(a, d, 64);
      if (l == 0) sd[n * 24 + o] = a;
    }
  }
}

// -------- Bt[j, k] = bf16(W[k, j])  — straight transpose, row length 768 --------
__global__ void k_trans(const float* __restrict__ W, u16* __restrict__ Bt) {
  int kt = blockIdx.x * 32, jt = blockIdx.y * 32;
  int tx = threadIdx.x, ty = threadIdx.y;  // 32, 8
  __shared__ float tile[32][33];
#pragma unroll
  for (int r = 0; r < 4; r++)
    tile[ty + 8 * r][tx] = W[(size_t)(kt + ty + 8 * r) * KDIM + jt + tx];
  __syncthreads();
#pragma unroll
  for (int r = 0; r < 4; r++)
    Bt[(size_t)(jt + ty + 8 * r) * FDIM + kt + tx] = f32_bf16(tile[tx][ty + 8 * r]);
}

// ---- GEMM: Hbig[MPAD, 9216] bf16 = xbf[MPAD,768] @ Bt[9216,768]^T.
//      r7-proven K-loop (register staging, 2 sets), NIT=24, NO split-K / atomics.
//      A (15 MB) + B (14 MB) are L2-resident -> staging loads are L2 hits. ----
__global__ __launch_bounds__(256, 3) void k_gemm(const u16* __restrict__ A,
    const u16* __restrict__ B, u16* __restrict__ C) {
  __shared__ __align__(16) u16 As[2][128 * 32];
  __shared__ __align__(16) u16 Bs[2][128 * 32];
  int t = threadIdx.x;
  int w = t >> 6, l = t & 63;
  int col0 = blockIdx.x * 128;   // 72 col tiles
  int row0 = blockIdx.y * 128;   // 79 row tiles
  int wm = (w >> 1) * 64, wn = (w & 1) * 64;
  f32x4 acc[4][4] = {};
  int idx0 = t * 8;                    // elem index in 128x32 tile, chunk 0 (rows 0-63)
  int idx1 = idx0 + 2048;              // chunk 1 (rows 64-127)
  const u16* Ag0 = A + (size_t)(row0 + (idx0 >> 5)) * FDIM + (idx0 & 31);
  const u16* Ag1 = A + (size_t)(row0 + (idx1 >> 5)) * FDIM + (idx1 & 31);
  const u16* Bg0 = B + (size_t)(col0 + (idx0 >> 5)) * FDIM + (idx0 & 31);
  const u16* Bg1 = B + (size_t)(col0 + (idx1 >> 5)) * FDIM + (idx1 & 31);
  int lr = l & 15, lk = (l >> 4) * 8;

  short8 ra0, ra1, rb0, rb1;           // staging registers (tile in flight)
  auto gload = [&](int k0) {
    ra0 = *(const short8*)(Ag0 + k0);
    ra1 = *(const short8*)(Ag1 + k0);
    rb0 = *(const short8*)(Bg0 + k0);
    rb1 = *(const short8*)(Bg1 + k0);
  };
  auto swrite = [&](int buf) {
    *(short8*)(&As[buf][idx0]) = ra0;
    *(short8*)(&As[buf][idx1]) = ra1;
    *(short8*)(&Bs[buf][idx0]) = rb0;
    *(short8*)(&Bs[buf][idx1]) = rb1;
  };

  gload(0);
  swrite(0);
  gload(32);
  __syncthreads();
  const int NIT = FDIM / 32;  // 24
  int cur = 0;
  for (int it = 0; it < NIT; it++) {
    short8 af[4], bf[4];
#pragma unroll
    for (int i = 0; i < 4; i++) af[i] = *(const short8*)(&As[cur][(wm + i * 16 + lr) * 32 + lk]);
#pragma unroll
    for (int j = 0; j < 4; j++) bf[j] = *(const short8*)(&Bs[cur][(wn + j * 16 + lr) * 32 + lk]);
#pragma unroll
    for (int i = 0; i < 4; i++)
#pragma unroll
      for (int j = 0; j < 4; j++)
        acc[i][j] = __builtin_amdgcn_mfma_f32_16x16x32_bf16(af[i], bf[j], acc[i][j], 0, 0, 0);
    if (it + 1 < NIT) {
      swrite(cur ^ 1);
      if (it + 2 < NIT) gload((it + 2) * 32);
    }
    __syncthreads();
    cur ^= 1;
  }

  int lg = l >> 4;
#pragma unroll
  for (int i = 0; i < 4; i++)
#pragma unroll
    for (int j = 0; j < 4; j++) {
      int col = col0 + wn + j * 16 + lr;
#pragma unroll
      for (int r = 0; r < 4; r++) {
        int row = row0 + wm + i * 16 + lg * 4 + r;
        C[(size_t)row * KDIM + col] = f32_bf16(acc[i][j][r]);
      }
    }
}

// ---- fused attention softmax + aggregation + head-mean + bias, ONE WAVE PER NODE.
//      out[n,c] = (1/12) sum_h sum_e alpha[e,h] * Hbig[src_e, h*768+c] + bias[c]  ----
__global__ void k_att(const u16* __restrict__ Hbig, const int* __restrict__ ei,
                      const int* __restrict__ offs, const int* __restrict__ elist,
                      const float* __restrict__ sd, const float* __restrict__ bias,
                      float* __restrict__ out) {
  int t = threadIdx.x, w = t >> 6, l = t & 63;
  int n = blockIdx.x * 4 + w;
  __shared__ int   srcsS[4][DMAX];
  __shared__ float alphS[4][NHEADS * DMAX];
  if (n >= NNODES) return;          // no block barriers below
  int* srcs = srcsS[w];
  float* alph = alphS[w];
  int beg = offs[n];
  int deg = offs[n + 1] - beg;
  if (deg > DMAX) deg = DMAX;
  if (l < deg) {
    int e = elist[beg + l];
    srcs[l] = (e < NEDGES) ? ei[e] : e - NEDGES;
  }
  __builtin_amdgcn_wave_barrier();
  for (int p = l; p < deg * NHEADS; p += 64) {
    int i = p / NHEADS, h = p - i * NHEADS;
    float v = sd[srcs[i] * 24 + h] + sd[n * 24 + 12 + h];
    v = (v > 0.f) ? v : NEG_SLOPE * v;
    alph[h * DMAX + i] = v;
  }
  __builtin_amdgcn_wave_barrier();
  if (l < NHEADS) {
    float m = -1e30f;
    for (int i = 0; i < deg; i++) m = fmaxf(m, alph[l * DMAX + i]);
    float s = 0.f;
    for (int i = 0; i < deg; i++) {
      float ex = expf(alph[l * DMAX + i] - m);
      alph[l * DMAX + i] = ex;
      s += ex;
    }
    float inv = 1.f / (s + 1e-16f);
    for (int i = 0; i < deg; i++) alph[l * DMAX + i] *= inv;
  }
  __builtin_amdgcn_wave_barrier();
  // 3 passes of 256 cols; lane l covers cols [4l, 4l+4)
#pragma unroll
  for (int pass = 0; pass < 3; pass++) {
    float4 acc = make_float4(0.f, 0.f, 0.f, 0.f);
    for (int i = 0; i < deg; i++) {
      const u16* hb = Hbig + (size_t)srcs[i] * KDIM + pass * 256 + 4 * l;
#pragma unroll
      for (int h = 0; h < NHEADS; h++) {
        ushort4 hv = *(const ushort4*)(hb + h * CDIM);
        float a = alph[h * DMAX + i];
        acc.x += a * bf16_f32(hv.x);
        acc.y += a * bf16_f32(hv.y);
        acc.z += a * bf16_f32(hv.z);
        acc.w += a * bf16_f32(hv.w);
      }
    }
    int c = pass * 256 + 4 * l;
    const float sc = 1.f / 12.f;
    float4 ov;
    ov.x = acc.x * sc + bias[c + 0];
    ov.y = acc.y * sc + bias[c + 1];
    ov.z = acc.z * sc + bias[c + 2];
    ov.w = acc.w * sc + bias[c + 3];
    *(float4*)(out + (size_t)n * FDIM + c) = ov;
  }
}

// ---------------- graph mean pool (batch is sorted) ----------------
__global__ void k_pool(const float* __restrict__ h2, const int* __restrict__ batch,
                       float* __restrict__ g) {
  int gi = blockIdx.x;
  int c = blockIdx.y * 256 + threadIdx.x;
  int lo = 0, hi = NNODES;
  while (lo < hi) { int mid = (lo + hi) >> 1; if (batch[mid] < gi) lo = mid + 1; else hi = mid; }
  int start = lo;
  lo = start; hi = NNODES;
  while (lo < hi) { int mid = (lo + hi) >> 1; if (batch[mid] < gi + 1) lo = mid + 1; else hi = mid; }
  int end = lo;
  int cnt = end - start; if (cnt < 1) cnt = 1;
  float inv = 1.f / (float)cnt;
  float s = 0.f;
  for (int n = start; n < end; n++) s += h2[(size_t)n * FDIM + c];
  g[gi * FDIM + c] = s * inv;
}

// ---------------- MLP head ----------------
__global__ void k_mlp(const float* __restrict__ g, const float* __restrict__ w1,
                      const float* __restrict__ b1, const float* __restrict__ w2,
                      const float* __restrict__ b2, float* __restrict__ out) {
  int gi = blockIdx.x;
  int t = threadIdx.x;  // 128
  __shared__ float gs[FDIM];
  __shared__ float zs[128];
  for (int i = t; i < FDIM; i += 128) gs[i] = g[gi * FDIM + i];
  __syncthreads();
  float a = b1[t];
  for (int k = 0; k < FDIM; k++) a += gs[k] * w1[k * 128 + t];
  zs[t] = (a > 0.f) ? a : 0.f;
  __syncthreads();
  if (t < 4) {
    float o = b2[t];
    for (int i = 0; i < 128; i++) o += zs[i] * w2[i * 4 + t];
    out[gi * 4 + t] = o;
  }
}

extern "C" void kernel_launch(void* const* d_in, const int* in_sizes, int n_in,
                              void* d_out, int out_size, void* d_ws, size_t ws_size,
                              hipStream_t stream) {
  const float* x    = (const float*)d_in[0];
  const int*   ei   = (const int*)d_in[1];
  const int*   batch= (const int*)d_in[2];
  const float* W1   = (const float*)d_in[3];
  const float* as1  = (const float*)d_in[4];
  const float* ad1  = (const float*)d_in[5];
  const float* b1   = (const float*)d_in[6];
  const float* W2   = (const float*)d_in[7];
  const float* as2  = (const float*)d_in[8];
  const float* ad2  = (const float*)d_in[9];
  const float* b2   = (const float*)d_in[10];
  const float* mw1  = (const float*)d_in[11];
  const float* mb1  = (const float*)d_in[12];
  const float* mw2  = (const float*)d_in[13];
  const float* mb2  = (const float*)d_in[14];
  float* out = (float*)d_out;
  (void)in_sizes; (void)n_in; (void)out_size; (void)ws_size;

  char* wsb = (char*)d_ws;
  size_t off = 0;
  auto alloc = [&](size_t bytes) -> void* {
    void* p = wsb + off;
    off += (bytes + 255) & ~(size_t)255;
    return p;
  };
  // ws budget ~256 MiB: Hbig 186.4 + Bt 14.2 + h1 30.7 + h2 30.7 + small ≈ 263 MB.
  // xbf (15.5 MB) ALIASES h2: xbf is dead after k_gemm; h2 written only by layer-1
  // k_att (after gemm) and read by k_pool. No liveness overlap.
  u16*  Hbig   = (u16*)alloc((size_t)MPAD * KDIM * 2);     // 186.4 MB
  u16*  Bt     = (u16*)alloc((size_t)KDIM * FDIM * 2);     // 14.2 MB
  float* h1    = (float*)alloc((size_t)NNODES * FDIM * 4); // 30.7 MB
  float* h2    = (float*)alloc((size_t)NNODES * FDIM * 4); // 30.7 MB
  u16*  xbf    = (u16*)h2;                                 // alias (see above)
  float* sd    = (float*)alloc((size_t)NNODES * 24 * 4);
  float* Ut    = (float*)alloc((size_t)FDIM * 24 * 4);
  int*  counts = (int*)alloc((size_t)NNODES * 4);
  int*  offs   = (int*)alloc((size_t)(NNODES + 1) * 4);
  int*  cursor = (int*)alloc((size_t)NNODES * 4);
  int*  elist  = (int*)alloc((size_t)ETOT * 4);
  float* gbuf  = (float*)alloc((size_t)NGRAPH * FDIM * 4);

  // CSR by dst (edges identical for both layers)
  hipMemsetAsync(counts, 0, NNODES * 4, stream);
  k_count<<<(ETOT + 255) / 256, 256, 0, stream>>>(ei + NEDGES, counts);
  k_scan<<<1, 256, 0, stream>>>(counts, offs);
  k_seed<<<(NNODES + 255) / 256, 256, 0, stream>>>(offs, cursor);
  k_scatter<<<(ETOT + 255) / 256, 256, 0, stream>>>(ei + NEDGES, cursor, elist);

  for (int layer = 0; layer < 2; layer++) {
    const float* xin  = layer ? h1  : x;
    const float* W    = layer ? W2  : W1;
    const float* asrc = layer ? as2 : as1;
    const float* adst = layer ? ad2 : ad1;
    const float* bb   = layer ? b2  : b1;
    float* hout       = layer ? h2  : h1;

    k_U<<<FDIM, 256, 0, stream>>>(W, asrc, adst, Ut);
    k_sd<<<(NNODES + 19) / 20, 256, 0, stream>>>(xin, Ut, sd, xbf);
    k_trans<<<dim3(FDIM / 32, KDIM / 32), dim3(32, 8), 0, stream>>>(W, Bt);
    k_gemm<<<dim3(KDIM / 128, MPAD / 128), 256, 0, stream>>>(xbf, Bt, Hbig);
    k_att<<<(NNODES + 3) / 4, 256, 0, stream>>>(Hbig, ei, offs, elist, sd, bb, hout);
  }

  k_pool<<<dim3(NGRAPH, 3), 256, 0, stream>>>(h2, batch, gbuf);
  k_mlp<<<NGRAPH, 128, 0, stream>>>(gbuf, mw1, mb1, mw2, mb2, out);
}

// Round 13
// 907.283 us; speedup vs baseline: 1.0462x; 1.0071x over previous
//
#include <hip/hip_runtime.h>
#include <stdint.h>

typedef unsigned short u16;
typedef unsigned int   u32;

#define NNODES 10000
#define NEDGES 20000
#define ETOT   30000
#define NHEADS 12
#define CDIM   768
#define FDIM   768
#define KDIM   9216
#define NGRAPH 64
#define MPAD   10112   // 79*128 >= NNODES ; keeps total ws <= 264 MB (256 MiB budget!)
#define NEG_SLOPE 0.2f
#define DMAX   32      // max in-degree incl. self-loop; max of 10000 Poisson(2) ~ 14

typedef __attribute__((ext_vector_type(8))) short short8;
typedef __attribute__((ext_vector_type(4))) float f32x4;

__device__ __forceinline__ u16 f32_bf16(float f) {
  u32 u = __float_as_uint(f);
  u = (u + 0x7FFFu + ((u >> 16) & 1u)) >> 16;
  return (u16)u;
}
__device__ __forceinline__ float bf16_f32(u16 v) {
  return __uint_as_float(((u32)v) << 16);
}

// ---------------- CSR build ----------------
__global__ void k_count(const int* __restrict__ dste, int* __restrict__ counts) {
  int e = blockIdx.x * blockDim.x + threadIdx.x;
  if (e >= ETOT) return;
  int dst;
  if (e < NEDGES) dst = dste[e]; else dst = e - NEDGES;
  atomicAdd(&counts[dst], 1);
}

__global__ void k_scan(const int* __restrict__ counts, int* __restrict__ offs) {
  __shared__ int part[256];
  int t = threadIdx.x;
  const int chunk = 40;
  int beg = t * chunk;
  int end = beg + chunk; if (end > NNODES) end = NNODES;
  int s = 0;
  for (int i = beg; i < end && i < NNODES; i++) s += counts[i];
  part[t] = s;
  __syncthreads();
  for (int d = 1; d < 256; d <<= 1) {
    int v = (t >= d) ? part[t - d] : 0;
    __syncthreads();
    part[t] += v;
    __syncthreads();
  }
  int base = (t == 0) ? 0 : part[t - 1];
  for (int i = beg; i < end && i < NNODES; i++) { offs[i] = base; base += counts[i]; }
  if (t == 255) offs[NNODES] = base;
}

__global__ void k_seed(const int* __restrict__ offs, int* __restrict__ cursor) {
  int n = blockIdx.x * blockDim.x + threadIdx.x;
  if (n < NNODES) cursor[n] = offs[n];
}

__global__ void k_scatter(const int* __restrict__ dste, int* __restrict__ cursor,
                          int* __restrict__ elist) {
  int e = blockIdx.x * blockDim.x + threadIdx.x;
  if (e >= ETOT) return;
  int dst;
  if (e < NEDGES) dst = dste[e]; else dst = e - NEDGES;
  int pos = atomicAdd(&cursor[dst], 1);
  elist[pos] = e;
}

// ------- Ut[o*768+k] = sum_c W[k, h*768+c] * a[h, c] ; 4 waves x 6 o's per block -------
__global__ void k_U(const float* __restrict__ W, const float* __restrict__ a_src,
                    const float* __restrict__ a_dst, float* __restrict__ Ut) {
  int k = blockIdx.x;
  int t = threadIdx.x, w = t >> 6, l = t & 63;
  const float* Wrow = W + (size_t)k * KDIM;
#pragma unroll
  for (int q = 0; q < 6; q++) {
    int o = w * 6 + q;
    int h = (o < 12) ? o : o - 12;
    const float* av = (o < 12) ? (a_src + h * CDIM) : (a_dst + h * CDIM);
    const float* wr = Wrow + h * CDIM;
    float p = 0.f;
    for (int c = l; c < CDIM; c += 64) p += wr[c] * av[c];
#pragma unroll
    for (int d = 32; d > 0; d >>= 1) p += __shfl_down(p, d, 64);
    if (l == 0) Ut[o * FDIM + k] = p;
  }
}

// ---- sd: Ut staged in LDS once per block; 20 nodes/block. Also writes xbf (GEMM A). ----
__global__ void k_sd(const float* __restrict__ xin, const float* __restrict__ Ut,
                     float* __restrict__ sd, u16* __restrict__ xbf) {
  __shared__ float UtS[24 * FDIM];   // 73728 B
  int t = threadIdx.x, w = t >> 6, l = t & 63;
  const float4* U4 = (const float4*)Ut;
  float4* S4 = (float4*)UtS;
  for (int i = t; i < 24 * FDIM / 4; i += 256) S4[i] = U4[i];
  __syncthreads();
#pragma unroll
  for (int rep = 0; rep < 5; rep++) {
    int n = blockIdx.x * 20 + w * 5 + rep;
    if (n >= NNODES) continue;
    const float* xr = xin + (size_t)n * FDIM;
    float4 x0 = *(const float4*)(xr + 4 * l);
    float4 x1 = *(const float4*)(xr + 4 * l + 256);
    float4 x2 = *(const float4*)(xr + 4 * l + 512);
    // bf16 copy for the GEMM A operand
    u16* xb = xbf + (size_t)n * FDIM + 4 * l;
    ushort4 p0, p1, p2;
    p0.x = f32_bf16(x0.x); p0.y = f32_bf16(x0.y); p0.z = f32_bf16(x0.z); p0.w = f32_bf16(x0.w);
    p1.x = f32_bf16(x1.x); p1.y = f32_bf16(x1.y); p1.z = f32_bf16(x1.z); p1.w = f32_bf16(x1.w);
    p2.x = f32_bf16(x2.x); p2.y = f32_bf16(x2.y); p2.z = f32_bf16(x2.z); p2.w = f32_bf16(x2.w);
    *(ushort4*)xb = p0;
    *(ushort4*)(xb + 256) = p1;
    *(ushort4*)(xb + 512) = p2;
#pragma unroll
    for (int o = 0; o < 24; o++) {
      const float4* up = (const float4*)(UtS + o * FDIM + 4 * l);
      float4 u0 = up[0];
      float4 u1 = up[64];
      float4 u2 = up[128];
      float a = x0.x * u0.x + x0.y * u0.y + x0.z * u0.z + x0.w * u0.w
              + x1.x * u1.x + x1.y * u1.y + x1.z * u1.z + x1.w * u1.w
              + x2.x * u2.x + x2.y * u2.y + x2.z * u2.z + x2.w * u2.w;
#pragma unroll
      for (int d = 32; d > 0; d >>= 1) a += __shfl_xor(a, d, 64);
      if (l == 0) sd[n * 24 + o] = a;
    }
  }
}

// -------- Bt[j, k] = bf16(W[k, j])  — straight transpose, row length 768 --------
__global__ void k_trans(const float* __restrict__ W, u16* __restrict__ Bt) {
  int kt = blockIdx.x * 32, jt = blockIdx.y * 32;
  int tx = threadIdx.x, ty = threadIdx.y;  // 32, 8
  __shared__ float tile[32][33];
#pragma unroll
  for (int r = 0; r < 4; r++)
    tile[ty + 8 * r][tx] = W[(size_t)(kt + ty + 8 * r) * KDIM + jt + tx];
  __syncthreads();
#pragma unroll
  for (int r = 0; r < 4; r++)
    Bt[(size_t)(jt + ty + 8 * r) * FDIM + kt + tx] = f32_bf16(tile[tx][ty + 8 * r]);
}

// ---- GEMM: Hbig[MPAD, 9216] bf16 = xbf[MPAD,768] @ Bt[9216,768]^T.
//      r7-proven K-loop (register staging, 2 sets), NIT=24, no split-K.
//      XCD swizzle: xcd = lin&7 owns col-tiles [xcd*9, xcd*9+9) -> per-XCD B slice
//      1.77 MB (L2-resident); A-tile reused by 9 consecutive blocks (L2-hit). ----
__global__ __launch_bounds__(256, 3) void k_gemm(const u16* __restrict__ A,
    const u16* __restrict__ B, u16* __restrict__ C) {
  __shared__ __align__(16) u16 As[2][128 * 32];
  __shared__ __align__(16) u16 Bs[2][128 * 32];
  int t = threadIdx.x;
  int w = t >> 6, l = t & 63;
  int lin = blockIdx.x;                // 5688 = 8 * 711, 711 = 79 * 9
  int xcd = lin & 7;
  int s = lin >> 3;                    // 0..710
  int colt = xcd * 9 + (s % 9);        // 0..71 (col tile), fixed 9-tile slice per XCD
  int y = s / 9;                       // 0..78 (row tile), streamed
  int col0 = colt * 128;
  int row0 = y * 128;
  int wm = (w >> 1) * 64, wn = (w & 1) * 64;
  f32x4 acc[4][4] = {};
  int idx0 = t * 8;                    // elem index in 128x32 tile, chunk 0 (rows 0-63)
  int idx1 = idx0 + 2048;              // chunk 1 (rows 64-127)
  const u16* Ag0 = A + (size_t)(row0 + (idx0 >> 5)) * FDIM + (idx0 & 31);
  const u16* Ag1 = A + (size_t)(row0 + (idx1 >> 5)) * FDIM + (idx1 & 31);
  const u16* Bg0 = B + (size_t)(col0 + (idx0 >> 5)) * FDIM + (idx0 & 31);
  const u16* Bg1 = B + (size_t)(col0 + (idx1 >> 5)) * FDIM + (idx1 & 31);
  int lr = l & 15, lk = (l >> 4) * 8;

  short8 ra0, ra1, rb0, rb1;           // staging registers (tile in flight)
  auto gload = [&](int k0) {
    ra0 = *(const short8*)(Ag0 + k0);
    ra1 = *(const short8*)(Ag1 + k0);
    rb0 = *(const short8*)(Bg0 + k0);
    rb1 = *(const short8*)(Bg1 + k0);
  };
  auto swrite = [&](int buf) {
    *(short8*)(&As[buf][idx0]) = ra0;
    *(short8*)(&As[buf][idx1]) = ra1;
    *(short8*)(&Bs[buf][idx0]) = rb0;
    *(short8*)(&Bs[buf][idx1]) = rb1;
  };

  gload(0);
  swrite(0);
  gload(32);
  __syncthreads();
  const int NIT = FDIM / 32;  // 24
  int cur = 0;
  for (int it = 0; it < NIT; it++) {
    short8 af[4], bf[4];
#pragma unroll
    for (int i = 0; i < 4; i++) af[i] = *(const short8*)(&As[cur][(wm + i * 16 + lr) * 32 + lk]);
#pragma unroll
    for (int j = 0; j < 4; j++) bf[j] = *(const short8*)(&Bs[cur][(wn + j * 16 + lr) * 32 + lk]);
#pragma unroll
    for (int i = 0; i < 4; i++)
#pragma unroll
      for (int j = 0; j < 4; j++)
        acc[i][j] = __builtin_amdgcn_mfma_f32_16x16x32_bf16(af[i], bf[j], acc[i][j], 0, 0, 0);
    if (it + 1 < NIT) {
      swrite(cur ^ 1);
      if (it + 2 < NIT) gload((it + 2) * 32);
    }
    __syncthreads();
    cur ^= 1;
  }

  int lg = l >> 4;
#pragma unroll
  for (int i = 0; i < 4; i++)
#pragma unroll
    for (int j = 0; j < 4; j++) {
      int col = col0 + wn + j * 16 + lr;
#pragma unroll
      for (int r = 0; r < 4; r++) {
        int row = row0 + wm + i * 16 + lg * 4 + r;
        C[(size_t)row * KDIM + col] = f32_bf16(acc[i][j][r]);
      }
    }
}

// ---- fused attention softmax + aggregation + head-mean + bias, ONE WAVE PER NODE.
//      out[n,c] = (1/12) sum_h sum_e alpha[e,h] * Hbig[src_e, h*768+c] + bias[c]  ----
__global__ void k_att(const u16* __restrict__ Hbig, const int* __restrict__ ei,
                      const int* __restrict__ offs, const int* __restrict__ elist,
                      const float* __restrict__ sd, const float* __restrict__ bias,
                      float* __restrict__ out) {
  int t = threadIdx.x, w = t >> 6, l = t & 63;
  int n = blockIdx.x * 4 + w;
  __shared__ int   srcsS[4][DMAX];
  __shared__ float alphS[4][NHEADS * DMAX];
  if (n >= NNODES) return;          // no block barriers below
  int* srcs = srcsS[w];
  float* alph = alphS[w];
  int beg = offs[n];
  int deg = offs[n + 1] - beg;
  if (deg > DMAX) deg = DMAX;
  if (l < deg) {
    int e = elist[beg + l];
    srcs[l] = (e < NEDGES) ? ei[e] : e - NEDGES;
  }
  __builtin_amdgcn_wave_barrier();
  for (int p = l; p < deg * NHEADS; p += 64) {
    int i = p / NHEADS, h = p - i * NHEADS;
    float v = sd[srcs[i] * 24 + h] + sd[n * 24 + 12 + h];
    v = (v > 0.f) ? v : NEG_SLOPE * v;
    alph[h * DMAX + i] = v;
  }
  __builtin_amdgcn_wave_barrier();
  if (l < NHEADS) {
    float m = -1e30f;
    for (int i = 0; i < deg; i++) m = fmaxf(m, alph[l * DMAX + i]);
    float s = 0.f;
    for (int i = 0; i < deg; i++) {
      float ex = expf(alph[l * DMAX + i] - m);
      alph[l * DMAX + i] = ex;
      s += ex;
    }
    float inv = 1.f / (s + 1e-16f);
    for (int i = 0; i < deg; i++) alph[l * DMAX + i] *= inv;
  }
  __builtin_amdgcn_wave_barrier();
  // 3 passes of 256 cols; lane l covers cols [4l, 4l+4)
#pragma unroll
  for (int pass = 0; pass < 3; pass++) {
    float4 acc = make_float4(0.f, 0.f, 0.f, 0.f);
    for (int i = 0; i < deg; i++) {
      const u16* hb = Hbig + (size_t)srcs[i] * KDIM + pass * 256 + 4 * l;
#pragma unroll
      for (int h = 0; h < NHEADS; h++) {
        ushort4 hv = *(const ushort4*)(hb + h * CDIM);
        float a = alph[h * DMAX + i];
        acc.x += a * bf16_f32(hv.x);
        acc.y += a * bf16_f32(hv.y);
        acc.z += a * bf16_f32(hv.z);
        acc.w += a * bf16_f32(hv.w);
      }
    }
    int c = pass * 256 + 4 * l;
    const float sc = 1.f / 12.f;
    float4 ov;
    ov.x = acc.x * sc + bias[c + 0];
    ov.y = acc.y * sc + bias[c + 1];
    ov.z = acc.z * sc + bias[c + 2];
    ov.w = acc.w * sc + bias[c + 3];
    *(float4*)(out + (size_t)n * FDIM + c) = ov;
  }
}

// ---------------- graph mean pool (batch is sorted) ----------------
__global__ void k_pool(const float* __restrict__ h2, const int* __restrict__ batch,
                       float* __restrict__ g) {
  int gi = blockIdx.x;
  int c = blockIdx.y * 256 + threadIdx.x;
  int lo = 0, hi = NNODES;
  while (lo < hi) { int mid = (lo + hi) >> 1; if (batch[mid] < gi) lo = mid + 1; else hi = mid; }
  int start = lo;
  lo = start; hi = NNODES;
  while (lo < hi) { int mid = (lo + hi) >> 1; if (batch[mid] < gi + 1) lo = mid + 1; else hi = mid; }
  int end = lo;
  int cnt = end - start; if (cnt < 1) cnt = 1;
  float inv = 1.f / (float)cnt;
  float s = 0.f;
  for (int n = start; n < end; n++) s += h2[(size_t)n * FDIM + c];
  g[gi * FDIM + c] = s * inv;
}

// ---------------- MLP head ----------------
__global__ void k_mlp(const float* __restrict__ g, const float* __restrict__ w1,
                      const float* __restrict__ b1, const float* __restrict__ w2,
                      const float* __restrict__ b2, float* __restrict__ out) {
  int gi = blockIdx.x;
  int t = threadIdx.x;  // 128
  __shared__ float gs[FDIM];
  __shared__ float zs[128];
  for (int i = t; i < FDIM; i += 128) gs[i] = g[gi * FDIM + i];
  __syncthreads();
  float a = b1[t];
  for (int k = 0; k < FDIM; k++) a += gs[k] * w1[k * 128 + t];
  zs[t] = (a > 0.f) ? a : 0.f;
  __syncthreads();
  if (t < 4) {
    float o = b2[t];
    for (int i = 0; i < 128; i++) o += zs[i] * w2[i * 4 + t];
    out[gi * 4 + t] = o;
  }
}

extern "C" void kernel_launch(void* const* d_in, const int* in_sizes, int n_in,
                              void* d_out, int out_size, void* d_ws, size_t ws_size,
                              hipStream_t stream) {
  const float* x    = (const float*)d_in[0];
  const int*   ei   = (const int*)d_in[1];
  const int*   batch= (const int*)d_in[2];
  const float* W1   = (const float*)d_in[3];
  const float* as1  = (const float*)d_in[4];
  const float* ad1  = (const float*)d_in[5];
  const float* b1   = (const float*)d_in[6];
  const float* W2   = (const float*)d_in[7];
  const float* as2  = (const float*)d_in[8];
  const float* ad2  = (const float*)d_in[9];
  const float* b2   = (const float*)d_in[10];
  const float* mw1  = (const float*)d_in[11];
  const float* mb1  = (const float*)d_in[12];
  const float* mw2  = (const float*)d_in[13];
  const float* mb2  = (const float*)d_in[14];
  float* out = (float*)d_out;
  (void)in_sizes; (void)n_in; (void)out_size; (void)ws_size;

  char* wsb = (char*)d_ws;
  size_t off = 0;
  auto alloc = [&](size_t bytes) -> void* {
    void* p = wsb + off;
    off += (bytes + 255) & ~(size_t)255;
    return p;
  };
  // ws budget ~256 MiB: Hbig 186.4 + Bt 14.2 + h1 30.7 + h2 30.7 + small ≈ 263 MB.
  // xbf (15.5 MB) ALIASES h2: xbf is dead after k_gemm; h2 written only by layer-1
  // k_att (after gemm) and read by k_pool. No liveness overlap.
  u16*  Hbig   = (u16*)alloc((size_t)MPAD * KDIM * 2);     // 186.4 MB
  u16*  Bt     = (u16*)alloc((size_t)KDIM * FDIM * 2);     // 14.2 MB
  float* h1    = (float*)alloc((size_t)NNODES * FDIM * 4); // 30.7 MB
  float* h2    = (float*)alloc((size_t)NNODES * FDIM * 4); // 30.7 MB
  u16*  xbf    = (u16*)h2;                                 // alias (see above)
  float* sd    = (float*)alloc((size_t)NNODES * 24 * 4);
  float* Ut    = (float*)alloc((size_t)FDIM * 24 * 4);
  int*  counts = (int*)alloc((size_t)NNODES * 4);
  int*  offs   = (int*)alloc((size_t)(NNODES + 1) * 4);
  int*  cursor = (int*)alloc((size_t)NNODES * 4);
  int*  elist  = (int*)alloc((size_t)ETOT * 4);
  float* gbuf  = (float*)alloc((size_t)NGRAPH * FDIM * 4);

  // CSR by dst (edges identical for both layers)
  hipMemsetAsync(counts, 0, NNODES * 4, stream);
  k_count<<<(ETOT + 255) / 256, 256, 0, stream>>>(ei + NEDGES, counts);
  k_scan<<<1, 256, 0, stream>>>(counts, offs);
  k_seed<<<(NNODES + 255) / 256, 256, 0, stream>>>(offs, cursor);
  k_scatter<<<(ETOT + 255) / 256, 256, 0, stream>>>(ei + NEDGES, cursor, elist);

  for (int layer = 0; layer < 2; layer++) {
    const float* xin  = layer ? h1  : x;
    const float* W    = layer ? W2  : W1;
    const float* asrc = layer ? as2 : as1;
    const float* adst = layer ? ad2 : ad1;
    const float* bb   = layer ? b2  : b1;
    float* hout       = layer ? h2  : h1;

    k_U<<<FDIM, 256, 0, stream>>>(W, asrc, adst, Ut);
    k_sd<<<(NNODES + 19) / 20, 256, 0, stream>>>(xin, Ut, sd, xbf);
    k_trans<<<dim3(FDIM / 32, KDIM / 32), dim3(32, 8), 0, stream>>>(W, Bt);
    k_gemm<<<8 * 711, 256, 0, stream>>>(xbf, Bt, Hbig);
    k_att<<<(NNODES + 3) / 4, 256, 0, stream>>>(Hbig, ei, offs, elist, sd, bb, hout);
  }

  k_pool<<<dim3(NGRAPH, 3), 256, 0, stream>>>(h2, batch, gbuf);
  k_mlp<<<NGRAPH, 128, 0, stream>>>(gbuf, mw1, mb1, mw2, mb2, out);
}

// Round 14
// 876.987 us; speedup vs baseline: 1.0824x; 1.0345x over previous
//
#include <hip/hip_runtime.h>
#include <stdint.h>

typedef unsigned short u16;
typedef unsigned int   u32;

#define NNODES 10000
#define NEDGES 20000
#define ETOT   30000
#define NHEADS 12
#define CDIM   768
#define FDIM   768
#define KDIM   9216
#define NGRAPH 64
#define MPAD   10112   // 79*128 >= NNODES ; keeps total ws <= 264 MB (256 MiB budget!)
#define NEG_SLOPE 0.2f
#define DMAX   32      // max in-degree incl. self-loop; max of 10000 Poisson(2) ~ 14

typedef __attribute__((ext_vector_type(8))) short short8;
typedef __attribute__((ext_vector_type(4))) float f32x4;

__device__ __forceinline__ u16 f32_bf16(float f) {
  u32 u = __float_as_uint(f);
  u = (u + 0x7FFFu + ((u >> 16) & 1u)) >> 16;
  return (u16)u;
}
__device__ __forceinline__ float bf16_f32(u16 v) {
  return __uint_as_float(((u32)v) << 16);
}

// ---------------- CSR build ----------------
__global__ void k_count(const int* __restrict__ dste, int* __restrict__ counts) {
  int e = blockIdx.x * blockDim.x + threadIdx.x;
  if (e >= ETOT) return;
  int dst;
  if (e < NEDGES) dst = dste[e]; else dst = e - NEDGES;
  atomicAdd(&counts[dst], 1);
}

__global__ void k_scan(const int* __restrict__ counts, int* __restrict__ offs) {
  __shared__ int part[256];
  int t = threadIdx.x;
  const int chunk = 40;
  int beg = t * chunk;
  int end = beg + chunk; if (end > NNODES) end = NNODES;
  int s = 0;
  for (int i = beg; i < end && i < NNODES; i++) s += counts[i];
  part[t] = s;
  __syncthreads();
  for (int d = 1; d < 256; d <<= 1) {
    int v = (t >= d) ? part[t - d] : 0;
    __syncthreads();
    part[t] += v;
    __syncthreads();
  }
  int base = (t == 0) ? 0 : part[t - 1];
  for (int i = beg; i < end && i < NNODES; i++) { offs[i] = base; base += counts[i]; }
  if (t == 255) offs[NNODES] = base;
}

__global__ void k_seed(const int* __restrict__ offs, int* __restrict__ cursor) {
  int n = blockIdx.x * blockDim.x + threadIdx.x;
  if (n < NNODES) cursor[n] = offs[n];
}

__global__ void k_scatter(const int* __restrict__ dste, int* __restrict__ cursor,
                          int* __restrict__ elist) {
  int e = blockIdx.x * blockDim.x + threadIdx.x;
  if (e >= ETOT) return;
  int dst;
  if (e < NEDGES) dst = dste[e]; else dst = e - NEDGES;
  int pos = atomicAdd(&cursor[dst], 1);
  elist[pos] = e;
}

// ------- Ut[o*768+k] = sum_c W[k, h*768+c] * a[h, c] ; 4 waves x 6 o's per block -------
__global__ void k_U(const float* __restrict__ W, const float* __restrict__ a_src,
                    const float* __restrict__ a_dst, float* __restrict__ Ut) {
  int k = blockIdx.x;
  int t = threadIdx.x, w = t >> 6, l = t & 63;
  const float* Wrow = W + (size_t)k * KDIM;
#pragma unroll
  for (int q = 0; q < 6; q++) {
    int o = w * 6 + q;
    int h = (o < 12) ? o : o - 12;
    const float* av = (o < 12) ? (a_src + h * CDIM) : (a_dst + h * CDIM);
    const float* wr = Wrow + h * CDIM;
    float p = 0.f;
    for (int c = l; c < CDIM; c += 64) p += wr[c] * av[c];
#pragma unroll
    for (int d = 32; d > 0; d >>= 1) p += __shfl_down(p, d, 64);
    if (l == 0) Ut[o * FDIM + k] = p;
  }
}

// ---- sd: Ut staged in LDS once per block; 20 nodes/block. Also writes xbf (GEMM A). ----
__global__ void k_sd(const float* __restrict__ xin, const float* __restrict__ Ut,
                     float* __restrict__ sd, u16* __restrict__ xbf) {
  __shared__ float UtS[24 * FDIM];   // 73728 B
  int t = threadIdx.x, w = t >> 6, l = t & 63;
  const float4* U4 = (const float4*)Ut;
  float4* S4 = (float4*)UtS;
  for (int i = t; i < 24 * FDIM / 4; i += 256) S4[i] = U4[i];
  __syncthreads();
#pragma unroll
  for (int rep = 0; rep < 5; rep++) {
    int n = blockIdx.x * 20 + w * 5 + rep;
    if (n >= NNODES) continue;
    const float* xr = xin + (size_t)n * FDIM;
    float4 x0 = *(const float4*)(xr + 4 * l);
    float4 x1 = *(const float4*)(xr + 4 * l + 256);
    float4 x2 = *(const float4*)(xr + 4 * l + 512);
    // bf16 copy for the GEMM A operand
    u16* xb = xbf + (size_t)n * FDIM + 4 * l;
    ushort4 p0, p1, p2;
    p0.x = f32_bf16(x0.x); p0.y = f32_bf16(x0.y); p0.z = f32_bf16(x0.z); p0.w = f32_bf16(x0.w);
    p1.x = f32_bf16(x1.x); p1.y = f32_bf16(x1.y); p1.z = f32_bf16(x1.z); p1.w = f32_bf16(x1.w);
    p2.x = f32_bf16(x2.x); p2.y = f32_bf16(x2.y); p2.z = f32_bf16(x2.z); p2.w = f32_bf16(x2.w);
    *(ushort4*)xb = p0;
    *(ushort4*)(xb + 256) = p1;
    *(ushort4*)(xb + 512) = p2;
#pragma unroll
    for (int o = 0; o < 24; o++) {
      const float4* up = (const float4*)(UtS + o * FDIM + 4 * l);
      float4 u0 = up[0];
      float4 u1 = up[64];
      float4 u2 = up[128];
      float a = x0.x * u0.x + x0.y * u0.y + x0.z * u0.z + x0.w * u0.w
              + x1.x * u1.x + x1.y * u1.y + x1.z * u1.z + x1.w * u1.w
              + x2.x * u2.x + x2.y * u2.y + x2.z * u2.z + x2.w * u2.w;
#pragma unroll
      for (int d = 32; d > 0; d >>= 1) a += __shfl_xor(a, d, 64);
      if (l == 0) sd[n * 24 + o] = a;
    }
  }
}

// -------- Bt[j, k] = bf16(W[k, j])  — straight transpose, row length 768 --------
__global__ void k_trans(const float* __restrict__ W, u16* __restrict__ Bt) {
  int kt = blockIdx.x * 32, jt = blockIdx.y * 32;
  int tx = threadIdx.x, ty = threadIdx.y;  // 32, 8
  __shared__ float tile[32][33];
#pragma unroll
  for (int r = 0; r < 4; r++)
    tile[ty + 8 * r][tx] = W[(size_t)(kt + ty + 8 * r) * KDIM + jt + tx];
  __syncthreads();
#pragma unroll
  for (int r = 0; r < 4; r++)
    Bt[(size_t)(jt + ty + 8 * r) * FDIM + kt + tx] = f32_bf16(tile[tx][ty + 8 * r]);
}

// ---- GEMM: Hbig[MPAD, 9216] bf16 = xbf[MPAD,768] @ Bt[9216,768]^T.
//      Register staging (2 sets), NIT=24. Block tile 128x256, wave tile 64x128:
//      12 frag loads -> 32 MFMA = 0.56 KB LDS per MFMA (vs 0.75 at 64x64) —
//      attacks the measured LDS-BW wall. launch_bounds(256,2): acc 128 + frags 48
//      + staging 24 VGPR must not spill (r5/r8 lesson; WRITE_SIZE is the tripwire). ----
__global__ __launch_bounds__(256, 2) void k_gemm(const u16* __restrict__ A,
    const u16* __restrict__ B, u16* __restrict__ C) {
  __shared__ __align__(16) u16 As[2][128 * 32];   // 8 KB per buffer
  __shared__ __align__(16) u16 Bs[2][256 * 32];   // 16 KB per buffer
  int t = threadIdx.x;
  int w = t >> 6, l = t & 63;
  int col0 = blockIdx.x * 256;   // 36 col tiles
  int row0 = blockIdx.y * 128;   // 79 row tiles
  int wm = (w >> 1) * 64;        // wave rows: 0 or 64
  int wn = (w & 1) * 128;        // wave cols: 0 or 128
  f32x4 acc[4][8] = {};
  int idx0 = t * 8;              // A chunk0: tile rows 0-63 ; also B chunk0
  int idx1 = idx0 + 2048;        // A chunk1: tile rows 64-127
  const u16* Ag0 = A + (size_t)(row0 + (idx0 >> 5)) * FDIM + (idx0 & 31);
  const u16* Ag1 = A + (size_t)(row0 + (idx1 >> 5)) * FDIM + (idx1 & 31);
  const u16* Bg0 = B + (size_t)(col0 + (idx0 >> 5)) * FDIM + (idx0 & 31);
  const u16* Bg1 = B + (size_t)(col0 + ((idx0 + 2048) >> 5)) * FDIM + (idx0 & 31);
  const u16* Bg2 = B + (size_t)(col0 + ((idx0 + 4096) >> 5)) * FDIM + (idx0 & 31);
  const u16* Bg3 = B + (size_t)(col0 + ((idx0 + 6144) >> 5)) * FDIM + (idx0 & 31);
  int lr = l & 15, lk = (l >> 4) * 8;

  short8 ra0, ra1, rb0, rb1, rb2, rb3;   // staging registers (one tile in flight)
  auto gload = [&](int k0) {
    ra0 = *(const short8*)(Ag0 + k0);
    ra1 = *(const short8*)(Ag1 + k0);
    rb0 = *(const short8*)(Bg0 + k0);
    rb1 = *(const short8*)(Bg1 + k0);
    rb2 = *(const short8*)(Bg2 + k0);
    rb3 = *(const short8*)(Bg3 + k0);
  };
  auto swrite = [&](int buf) {
    *(short8*)(&As[buf][idx0]) = ra0;
    *(short8*)(&As[buf][idx1]) = ra1;
    *(short8*)(&Bs[buf][idx0]) = rb0;
    *(short8*)(&Bs[buf][idx0 + 2048]) = rb1;
    *(short8*)(&Bs[buf][idx0 + 4096]) = rb2;
    *(short8*)(&Bs[buf][idx0 + 6144]) = rb3;
  };

  gload(0);
  swrite(0);
  gload(32);
  __syncthreads();
  const int NIT = FDIM / 32;  // 24
  int cur = 0;
  for (int it = 0; it < NIT; it++) {
    short8 af[4], bf[8];
#pragma unroll
    for (int i = 0; i < 4; i++) af[i] = *(const short8*)(&As[cur][(wm + i * 16 + lr) * 32 + lk]);
#pragma unroll
    for (int j = 0; j < 8; j++) bf[j] = *(const short8*)(&Bs[cur][(wn + j * 16 + lr) * 32 + lk]);
#pragma unroll
    for (int i = 0; i < 4; i++)
#pragma unroll
      for (int j = 0; j < 8; j++)
        acc[i][j] = __builtin_amdgcn_mfma_f32_16x16x32_bf16(af[i], bf[j], acc[i][j], 0, 0, 0);
    if (it + 1 < NIT) {
      swrite(cur ^ 1);
      if (it + 2 < NIT) gload((it + 2) * 32);
    }
    __syncthreads();
    cur ^= 1;
  }

  int lg = l >> 4;
#pragma unroll
  for (int i = 0; i < 4; i++)
#pragma unroll
    for (int j = 0; j < 8; j++) {
      int col = col0 + wn + j * 16 + lr;
#pragma unroll
      for (int r = 0; r < 4; r++) {
        int row = row0 + wm + i * 16 + lg * 4 + r;
        C[(size_t)row * KDIM + col] = f32_bf16(acc[i][j][r]);
      }
    }
}

// ---- fused attention softmax + aggregation + head-mean + bias, ONE WAVE PER NODE.
//      out[n,c] = (1/12) sum_h sum_e alpha[e,h] * Hbig[src_e, h*768+c] + bias[c]  ----
__global__ void k_att(const u16* __restrict__ Hbig, const int* __restrict__ ei,
                      const int* __restrict__ offs, const int* __restrict__ elist,
                      const float* __restrict__ sd, const float* __restrict__ bias,
                      float* __restrict__ out) {
  int t = threadIdx.x, w = t >> 6, l = t & 63;
  int n = blockIdx.x * 4 + w;
  __shared__ int   srcsS[4][DMAX];
  __shared__ float alphS[4][NHEADS * DMAX];
  if (n >= NNODES) return;          // no block barriers below
  int* srcs = srcsS[w];
  float* alph = alphS[w];
  int beg = offs[n];
  int deg = offs[n + 1] - beg;
  if (deg > DMAX) deg = DMAX;
  if (l < deg) {
    int e = elist[beg + l];
    srcs[l] = (e < NEDGES) ? ei[e] : e - NEDGES;
  }
  __builtin_amdgcn_wave_barrier();
  for (int p = l; p < deg * NHEADS; p += 64) {
    int i = p / NHEADS, h = p - i * NHEADS;
    float v = sd[srcs[i] * 24 + h] + sd[n * 24 + 12 + h];
    v = (v > 0.f) ? v : NEG_SLOPE * v;
    alph[h * DMAX + i] = v;
  }
  __builtin_amdgcn_wave_barrier();
  if (l < NHEADS) {
    float m = -1e30f;
    for (int i = 0; i < deg; i++) m = fmaxf(m, alph[l * DMAX + i]);
    float s = 0.f;
    for (int i = 0; i < deg; i++) {
      float ex = expf(alph[l * DMAX + i] - m);
      alph[l * DMAX + i] = ex;
      s += ex;
    }
    float inv = 1.f / (s + 1e-16f);
    for (int i = 0; i < deg; i++) alph[l * DMAX + i] *= inv;
  }
  __builtin_amdgcn_wave_barrier();
  // 3 passes of 256 cols; lane l covers cols [4l, 4l+4)
#pragma unroll
  for (int pass = 0; pass < 3; pass++) {
    float4 acc = make_float4(0.f, 0.f, 0.f, 0.f);
    for (int i = 0; i < deg; i++) {
      const u16* hb = Hbig + (size_t)srcs[i] * KDIM + pass * 256 + 4 * l;
#pragma unroll
      for (int h = 0; h < NHEADS; h++) {
        ushort4 hv = *(const ushort4*)(hb + h * CDIM);
        float a = alph[h * DMAX + i];
        acc.x += a * bf16_f32(hv.x);
        acc.y += a * bf16_f32(hv.y);
        acc.z += a * bf16_f32(hv.z);
        acc.w += a * bf16_f32(hv.w);
      }
    }
    int c = pass * 256 + 4 * l;
    const float sc = 1.f / 12.f;
    float4 ov;
    ov.x = acc.x * sc + bias[c + 0];
    ov.y = acc.y * sc + bias[c + 1];
    ov.z = acc.z * sc + bias[c + 2];
    ov.w = acc.w * sc + bias[c + 3];
    *(float4*)(out + (size_t)n * FDIM + c) = ov;
  }
}

// ---------------- graph mean pool (batch is sorted) ----------------
__global__ void k_pool(const float* __restrict__ h2, const int* __restrict__ batch,
                       float* __restrict__ g) {
  int gi = blockIdx.x;
  int c = blockIdx.y * 256 + threadIdx.x;
  int lo = 0, hi = NNODES;
  while (lo < hi) { int mid = (lo + hi) >> 1; if (batch[mid] < gi) lo = mid + 1; else hi = mid; }
  int start = lo;
  lo = start; hi = NNODES;
  while (lo < hi) { int mid = (lo + hi) >> 1; if (batch[mid] < gi + 1) lo = mid + 1; else hi = mid; }
  int end = lo;
  int cnt = end - start; if (cnt < 1) cnt = 1;
  float inv = 1.f / (float)cnt;
  float s = 0.f;
  for (int n = start; n < end; n++) s += h2[(size_t)n * FDIM + c];
  g[gi * FDIM + c] = s * inv;
}

// ---------------- MLP head ----------------
__global__ void k_mlp(const float* __restrict__ g, const float* __restrict__ w1,
                      const float* __restrict__ b1, const float* __restrict__ w2,
                      const float* __restrict__ b2, float* __restrict__ out) {
  int gi = blockIdx.x;
  int t = threadIdx.x;  // 128
  __shared__ float gs[FDIM];
  __shared__ float zs[128];
  for (int i = t; i < FDIM; i += 128) gs[i] = g[gi * FDIM + i];
  __syncthreads();
  float a = b1[t];
  for (int k = 0; k < FDIM; k++) a += gs[k] * w1[k * 128 + t];
  zs[t] = (a > 0.f) ? a : 0.f;
  __syncthreads();
  if (t < 4) {
    float o = b2[t];
    for (int i = 0; i < 128; i++) o += zs[i] * w2[i * 4 + t];
    out[gi * 4 + t] = o;
  }
}

extern "C" void kernel_launch(void* const* d_in, const int* in_sizes, int n_in,
                              void* d_out, int out_size, void* d_ws, size_t ws_size,
                              hipStream_t stream) {
  const float* x    = (const float*)d_in[0];
  const int*   ei   = (const int*)d_in[1];
  const int*   batch= (const int*)d_in[2];
  const float* W1   = (const float*)d_in[3];
  const float* as1  = (const float*)d_in[4];
  const float* ad1  = (const float*)d_in[5];
  const float* b1   = (const float*)d_in[6];
  const float* W2   = (const float*)d_in[7];
  const float* as2  = (const float*)d_in[8];
  const float* ad2  = (const float*)d_in[9];
  const float* b2   = (const float*)d_in[10];
  const float* mw1  = (const float*)d_in[11];
  const float* mb1  = (const float*)d_in[12];
  const float* mw2  = (const float*)d_in[13];
  const float* mb2  = (const float*)d_in[14];
  float* out = (float*)d_out;
  (void)in_sizes; (void)n_in; (void)out_size; (void)ws_size;

  char* wsb = (char*)d_ws;
  size_t off = 0;
  auto alloc = [&](size_t bytes) -> void* {
    void* p = wsb + off;
    off += (bytes + 255) & ~(size_t)255;
    return p;
  };
  // ws budget ~256 MiB: Hbig 186.4 + Bt 14.2 + h1 30.7 + h2 30.7 + small ≈ 263 MB.
  // xbf (15.5 MB) ALIASES h2: xbf is dead after k_gemm; h2 written only by layer-1
  // k_att (after gemm) and read by k_pool. No liveness overlap.
  u16*  Hbig   = (u16*)alloc((size_t)MPAD * KDIM * 2);     // 186.4 MB
  u16*  Bt     = (u16*)alloc((size_t)KDIM * FDIM * 2);     // 14.2 MB
  float* h1    = (float*)alloc((size_t)NNODES * FDIM * 4); // 30.7 MB
  float* h2    = (float*)alloc((size_t)NNODES * FDIM * 4); // 30.7 MB
  u16*  xbf    = (u16*)h2;                                 // alias (see above)
  float* sd    = (float*)alloc((size_t)NNODES * 24 * 4);
  float* Ut    = (float*)alloc((size_t)FDIM * 24 * 4);
  int*  counts = (int*)alloc((size_t)NNODES * 4);
  int*  offs   = (int*)alloc((size_t)(NNODES + 1) * 4);
  int*  cursor = (int*)alloc((size_t)NNODES * 4);
  int*  elist  = (int*)alloc((size_t)ETOT * 4);
  float* gbuf  = (float*)alloc((size_t)NGRAPH * FDIM * 4);

  // CSR by dst (edges identical for both layers)
  hipMemsetAsync(counts, 0, NNODES * 4, stream);
  k_count<<<(ETOT + 255) / 256, 256, 0, stream>>>(ei + NEDGES, counts);
  k_scan<<<1, 256, 0, stream>>>(counts, offs);
  k_seed<<<(NNODES + 255) / 256, 256, 0, stream>>>(offs, cursor);
  k_scatter<<<(ETOT + 255) / 256, 256, 0, stream>>>(ei + NEDGES, cursor, elist);

  for (int layer = 0; layer < 2; layer++) {
    const float* xin  = layer ? h1  : x;
    const float* W    = layer ? W2  : W1;
    const float* asrc = layer ? as2 : as1;
    const float* adst = layer ? ad2 : ad1;
    const float* bb   = layer ? b2  : b1;
    float* hout       = layer ? h2  : h1;

    k_U<<<FDIM, 256, 0, stream>>>(W, asrc, adst, Ut);
    k_sd<<<(NNODES + 19) / 20, 256, 0, stream>>>(xin, Ut, sd, xbf);
    k_trans<<<dim3(FDIM / 32, KDIM / 32), dim3(32, 8), 0, stream>>>(W, Bt);
    k_gemm<<<dim3(KDIM / 256, MPAD / 128), 256, 0, stream>>>(xbf, Bt, Hbig);
    k_att<<<(NNODES + 3) / 4, 256, 0, stream>>>(Hbig, ei, offs, elist, sd, bb, hout);
  }

  k_pool<<<dim3(NGRAPH, 3), 256, 0, stream>>>(h2, batch, gbuf);
  k_mlp<<<NGRAPH, 128, 0, stream>>>(gbuf, mw1, mb1, mw2, mb2, out);
}